// Round 15
// baseline (219.577 us; speedup 1.0000x reference)
//
#include <hip/hip_runtime.h>
#include <math.h>

#define LATENT   1024
#define WORD     64
#define NB_WORD  8192
#define BATCH    2048
#define NROWS    (BATCH * LATENT / WORD)   // 32768
#define NELEM    (BATCH * LATENT)          // 2097152

#define NCHUNK   8
#define CWCHUNK  (NB_WORD / NCHUNK)        // 1024
#define TPC      32                        // 32-cw tiles per chunk
#define PKTS     (NB_WORD / 32 * 768)      // 196608 16B packets (3 MB)

typedef __attribute__((ext_vector_type(8)))  __bf16 bf16x8;
typedef __attribute__((ext_vector_type(16))) float  f32x16;

// ------- kernel 1: fused e2 + epack (one emb read, r1 e2 chain order) -
// thread m owns codeword m. 32-cw tiles for the 32x32x16 MFMA:
// packet ((tile*3+spl)*4+ks)*64 + hi*32 + col holds 8 bf16 of split spl
// for (cw = tile*32+col, k = ks*16 + hi*8 + e)  [B-frag lane order].
__global__ __launch_bounds__(256) void vq_prep_kernel(
    const float* __restrict__ emb, float* __restrict__ e2,
    bf16x8* __restrict__ epack) {
    int m = blockIdx.x * 256 + threadIdx.x;
    int tile = m >> 5, col = m & 31;
    float s0 = 0.f, s1 = 0.f, s2 = 0.f, s3 = 0.f;
#pragma unroll
    for (int g = 0; g < 8; ++g) {          // k-group of 8, k ascending
        const float4* s4 = reinterpret_cast<const float4*>(
            emb + (size_t)m * WORD + g * 8);
        float4 a = s4[0], b = s4[1];
        float tv[8] = {a.x, a.y, a.z, a.w, b.x, b.y, b.z, b.w};
        bf16x8 oh, om, ol;
#pragma unroll
        for (int e = 0; e < 8; ++e) {
            float v = tv[e];
            // e2 partial chains (same as r1: s_{k&3}, k ascending)
            if ((e & 3) == 0) s0 = fmaf(v, v, s0);
            else if ((e & 3) == 1) s1 = fmaf(v, v, s1);
            else if ((e & 3) == 2) s2 = fmaf(v, v, s2);
            else s3 = fmaf(v, v, s3);
            __bf16 h  = (__bf16)v;
            float r1  = v - (float)h;
            __bf16 mm = (__bf16)r1;
            float r2  = r1 - (float)mm;
            oh[e] = h; om[e] = mm; ol[e] = (__bf16)r2;
        }
        int ks = g >> 1, hi = g & 1;
        size_t pb = (size_t)tile * 768;
        epack[pb + (size_t)(0 * 4 + ks) * 64 + hi * 32 + col] = oh;
        epack[pb + (size_t)(1 * 4 + ks) * 64 + hi * 32 + col] = om;
        epack[pb + (size_t)(2 * 4 + ks) * 64 + hi * 32 + col] = ol;
    }
    e2[m] = (s0 + s1) + (s2 + s3);
}

__device__ __forceinline__ void gload_lds16(const char* g, char* l) {
    __builtin_amdgcn_global_load_lds(
        (const __attribute__((address_space(1))) void*)g,
        (__attribute__((address_space(3))) void*)l, 16, 0, 0);
}

#define MFMA32 __builtin_amdgcn_mfma_f32_32x32x16_bf16

// ---------------- kernel 2: MFMA split-bf16 argmin (32x32x16) ---------
// 256 thr = 4 waves; block = 128 rows x 1024-cw chunk; wave = 32 rows x
// 32-cw tiles (32 tiles). Per phase: vmcnt(0) drain -> raw barrier ->
// DMA(t+1) (3x gload_lds, 12 KB) -> 12 ds_read_b128 B-frags -> 24 MFMA
// (6 split-combos x 4 Ksteps, single acc chain) -> fold 16 slices.
__global__ __launch_bounds__(256)
__attribute__((amdgpu_waves_per_eu(3, 3)))
void vq_argmin_kernel(
    const float* __restrict__ z, const bf16x8* __restrict__ epack,
    const float* __restrict__ e2, unsigned long long* __restrict__ best) {

    // phase stagger: rounds are equal-length, so initial offsets persist
    {
        int ph = blockIdx.x & 3;
        if (ph == 1) __builtin_amdgcn_s_sleep(2);
        else if (ph == 2) __builtin_amdgcn_s_sleep(4);
        else if (ph == 3) __builtin_amdgcn_s_sleep(6);
    }

    __shared__ __align__(16) char le[2 * 12288];

    const int tid   = threadIdx.x;
    const int lane  = tid & 63;
    const int wband = tid >> 6;               // 0..3
    const int l31   = lane & 31;
    const int hi    = lane >> 5;              // 0..1
    const int rowbase   = blockIdx.x * 128 + wband * 32;
    const int tile0     = blockIdx.y * TPC;
    const int chunkbase = blockIdx.y * CWCHUNK;
    const float* e2g    = e2 + chunkbase;
    const int off       = (blockIdx.x & 7) * 4;   // tile start offset (L2 spread)

    // ---- build A-frags (z 3-way bf16 split): row = l31, k = ks*16+hi*8+e
    bf16x8 A[4][3];                            // [ks][spl]
    {
        const float4* zf4 = reinterpret_cast<const float4*>(
            z + (size_t)(rowbase + l31) * WORD);
#pragma unroll
        for (int ks = 0; ks < 4; ++ks) {
            float4 v0 = zf4[ks * 4 + hi * 2];
            float4 v1 = zf4[ks * 4 + hi * 2 + 1];
            float tv[8] = {v0.x, v0.y, v0.z, v0.w, v1.x, v1.y, v1.z, v1.w};
#pragma unroll
            for (int e = 0; e < 8; ++e) {
                float v = tv[e];
                __bf16 h  = (__bf16)v;
                float r1  = v - (float)h;
                __bf16 m  = (__bf16)r1;
                float r2  = r1 - (float)m;
                A[ks][0][e] = h;
                A[ks][1][e] = m;
                A[ks][2][e] = (__bf16)r2;
            }
        }
    }

    // ---- prologue: DMA tile 'off' into buf 0 + its e2 ----
    {
        const char* src = (const char*)epack + (size_t)(tile0 + off) * 12288 + tid * 16;
        char* dst = le + (tid & ~63) * 16;
        gload_lds16(src,        dst);
        gload_lds16(src + 4096, dst + 4096);
        gload_lds16(src + 8192, dst + 8192);
    }
    float e2A = e2g[off * 32 + l31];
    float e2B;

    float bestd[16];
    int   bt[16];
#pragma unroll
    for (int v = 0; v < 16; ++v) { bestd[v] = INFINITY; bt[v] = 0; }

// phase: drain DMA(TCUR), barrier, stage TNXT + its e2 into E2N,
// compute tile TCUR from buf BUFOFF, fold with E2C (loaded last phase).
#define PHASE(BUFOFF, E2C, E2N, TCUR, TNXT)                                 \
    {                                                                       \
        asm volatile("s_waitcnt vmcnt(0)" ::: "memory");                    \
        __builtin_amdgcn_sched_barrier(0);                                  \
        __builtin_amdgcn_s_barrier();      /* buf BUFOFF fully staged */    \
        const char* srcn = (const char*)epack +                             \
                           (size_t)(tile0 + (TNXT)) * 12288 + tid * 16;     \
        char* dstn = le + ((BUFOFF) ^ 12288) + (tid & ~63) * 16;            \
        gload_lds16(srcn,        dstn);                                     \
        gload_lds16(srcn + 4096, dstn + 4096);                              \
        gload_lds16(srcn + 8192, dstn + 8192);                              \
        E2N = e2g[(TNXT) * 32 + l31];                                       \
        const char* bb = le + (BUFOFF) + lane * 16;                         \
        bf16x8 Bh0 = *reinterpret_cast<const bf16x8*>(bb);                  \
        bf16x8 Bh1 = *reinterpret_cast<const bf16x8*>(bb + 1024);           \
        bf16x8 Bh2 = *reinterpret_cast<const bf16x8*>(bb + 2048);           \
        bf16x8 Bh3 = *reinterpret_cast<const bf16x8*>(bb + 3072);           \
        bf16x8 Bm0 = *reinterpret_cast<const bf16x8*>(bb + 4096);           \
        bf16x8 Bm1 = *reinterpret_cast<const bf16x8*>(bb + 5120);           \
        bf16x8 Bm2 = *reinterpret_cast<const bf16x8*>(bb + 6144);           \
        bf16x8 Bm3 = *reinterpret_cast<const bf16x8*>(bb + 7168);           \
        bf16x8 Bl0 = *reinterpret_cast<const bf16x8*>(bb + 8192);           \
        bf16x8 Bl1 = *reinterpret_cast<const bf16x8*>(bb + 9216);           \
        bf16x8 Bl2 = *reinterpret_cast<const bf16x8*>(bb + 10240);          \
        bf16x8 Bl3 = *reinterpret_cast<const bf16x8*>(bb + 11264);          \
        f32x16 acc = {0.f,0.f,0.f,0.f,0.f,0.f,0.f,0.f,                      \
                      0.f,0.f,0.f,0.f,0.f,0.f,0.f,0.f};                     \
        __builtin_amdgcn_s_setprio(1);                                      \
        /* per ks: hh, mh, lh, mm, hm, hl */                                \
        acc = MFMA32(A[0][0], Bh0, acc, 0, 0, 0);                           \
        acc = MFMA32(A[0][1], Bh0, acc, 0, 0, 0);                           \
        acc = MFMA32(A[0][2], Bh0, acc, 0, 0, 0);                           \
        acc = MFMA32(A[0][1], Bm0, acc, 0, 0, 0);                           \
        acc = MFMA32(A[0][0], Bm0, acc, 0, 0, 0);                           \
        acc = MFMA32(A[0][0], Bl0, acc, 0, 0, 0);                           \
        acc = MFMA32(A[1][0], Bh1, acc, 0, 0, 0);                           \
        acc = MFMA32(A[1][1], Bh1, acc, 0, 0, 0);                           \
        acc = MFMA32(A[1][2], Bh1, acc, 0, 0, 0);                           \
        acc = MFMA32(A[1][1], Bm1, acc, 0, 0, 0);                           \
        acc = MFMA32(A[1][0], Bm1, acc, 0, 0, 0);                           \
        acc = MFMA32(A[1][0], Bl1, acc, 0, 0, 0);                           \
        acc = MFMA32(A[2][0], Bh2, acc, 0, 0, 0);                           \
        acc = MFMA32(A[2][1], Bh2, acc, 0, 0, 0);                           \
        acc = MFMA32(A[2][2], Bh2, acc, 0, 0, 0);                           \
        acc = MFMA32(A[2][1], Bm2, acc, 0, 0, 0);                           \
        acc = MFMA32(A[2][0], Bm2, acc, 0, 0, 0);                           \
        acc = MFMA32(A[2][0], Bl2, acc, 0, 0, 0);                           \
        acc = MFMA32(A[3][0], Bh3, acc, 0, 0, 0);                           \
        acc = MFMA32(A[3][1], Bh3, acc, 0, 0, 0);                           \
        acc = MFMA32(A[3][2], Bh3, acc, 0, 0, 0);                           \
        acc = MFMA32(A[3][1], Bm3, acc, 0, 0, 0);                           \
        acc = MFMA32(A[3][0], Bm3, acc, 0, 0, 0);                           \
        acc = MFMA32(A[3][0], Bl3, acc, 0, 0, 0);                           \
        __builtin_amdgcn_s_setprio(0);                                      \
        _Pragma("unroll")                                                   \
        for (int v = 0; v < 16; ++v) {                                      \
            float d = fmaf(-2.0f, acc[v], E2C);                             \
            if (d < bestd[v]) { bestd[v] = d; bt[v] = (TCUR); }             \
        }                                                                   \
    }

    int t0 = off;
    for (int tt = 0; tt < TPC; tt += 2) {
        int t1 = (t0 + 1) & (TPC - 1);
        int t2 = (t0 + 2) & (TPC - 1);       // wrap: harmless reload
        PHASE(0,     e2A, e2B, t0, t1);
        PHASE(12288, e2B, e2A, t1, t2);
        t0 = t2;
    }
#undef PHASE

    // ---- cross-lane min over the 32 col-lanes of each half, merge ----
    // D layout: col = l31, row = (v&3) + 8*(v>>2) + 4*hi. u64 pack: min
    // dist, tie -> min cw == first occurrence; visit-order independent.
#pragma unroll
    for (int v = 0; v < 16; ++v) {
        float bd = bestd[v];
        int   cw = chunkbase + bt[v] * 32 + l31;
        unsigned db = __float_as_uint(bd);
        db = (db & 0x80000000u) ? ~db : (db | 0x80000000u);
        unsigned long long key =
            ((unsigned long long)db << 32) | (unsigned)cw;
#pragma unroll
        for (int o = 1; o < 32; o <<= 1) {
            unsigned long long other = __shfl_xor(key, o);
            key = (other < key) ? other : key;
        }
        if (l31 == 0)
            atomicMin(&best[rowbase + (v & 3) + 8 * (v >> 2) + 4 * hi], key);
    }
}

// ---------------- kernel 3: gather + straight-through output + loss ---
__global__ __launch_bounds__(256) void vq_out_kernel(
    const float* __restrict__ z, const float* __restrict__ emb,
    const unsigned long long* __restrict__ best,
    float* __restrict__ out, float* __restrict__ lsum) {
    const int base = (blockIdx.x * 256 + threadIdx.x) * 8;
    const int row  = base >> 6;
    const int m    = (int)(best[row] & 0xFFFFFFFFull);

    const float4* zp = reinterpret_cast<const float4*>(z + base);
    const float4* qp = reinterpret_cast<const float4*>(emb + (size_t)m * WORD + (base & 63));
    float4* op = reinterpret_cast<float4*>(out + base);

    float s = 0.f;
#pragma unroll
    for (int i = 0; i < 2; ++i) {
        float4 zv = zp[i];
        float4 qv = qp[i];
        float dx = qv.x - zv.x, dy = qv.y - zv.y, dz = qv.z - zv.z, dw = qv.w - zv.w;
        float4 ov;
        ov.x = zv.x + dx; ov.y = zv.y + dy; ov.z = zv.z + dz; ov.w = zv.w + dw;
        op[i] = ov;
        s += dx*dx + dy*dy + dz*dz + dw*dw;
    }

#pragma unroll
    for (int off = 32; off > 0; off >>= 1) s += __shfl_down(s, off);
    __shared__ float wsum[4];
    int lane = threadIdx.x & 63, wid = threadIdx.x >> 6;
    if (lane == 0) wsum[wid] = s;
    __syncthreads();
    if (threadIdx.x == 0)
        atomicAdd(lsum, (wsum[0] + wsum[1]) + (wsum[2] + wsum[3]));
}

// ---------------- kernel 4: finalize loss -----------------------------
__global__ void vq_loss_kernel(const float* __restrict__ lsum,
                               float* __restrict__ loss_out) {
    float mean = lsum[0] * (1.0f / (float)NELEM);
    loss_out[0] = mean + 2.5f * mean;
}

extern "C" void kernel_launch(void* const* d_in, const int* in_sizes, int n_in,
                              void* d_out, int out_size, void* d_ws, size_t ws_size,
                              hipStream_t stream) {
    const float* z   = (const float*)d_in[0];   // z_mean (2048,1024)
    // d_in[1] = z_log_var, unused by the reference
    const float* emb = (const float*)d_in[2];   // (8192,64)
    float* out = (float*)d_out;                 // [z_q_st flat (2097152), loss]

    // ws layout: epack 3 MB | e2 32 KB | best 256 KB | lsum 4 B
    bf16x8* epack = (bf16x8*)d_ws;
    float*  e2    = (float*)((char*)d_ws + (size_t)PKTS * 16);
    unsigned long long* best =
        (unsigned long long*)((char*)e2 + NB_WORD * sizeof(float));
    float* lsum = (float*)((char*)best + NROWS * sizeof(unsigned long long));

    hipMemsetAsync(best, 0xFF, NROWS * sizeof(unsigned long long), stream);
    hipMemsetAsync(lsum, 0, sizeof(float), stream);

    vq_prep_kernel<<<NB_WORD / 256, 256, 0, stream>>>(emb, e2, epack);
    vq_argmin_kernel<<<dim3(NROWS / 128, NCHUNK), 256, 0, stream>>>(
        z, epack, e2, best);
    vq_out_kernel<<<NELEM / (256 * 8), 256, 0, stream>>>(z, emb, best, out, lsum);
    vq_loss_kernel<<<1, 1, 0, stream>>>(lsum, out + NELEM);
}